// Round 3
// baseline (115.373 us; speedup 1.0000x reference)
//
#include <hip/hip_runtime.h>
#include <hip/hip_bf16.h>

// PCC loss: y_hat, y are fp32 [64, 3, 256, 256]. Output: scalar fp32 = 1 - mean_s(pcc_s).
// Single-pass 5-moment reduction, memory-bound (100.7 MB traffic, ~16us roofline).

constexpr int B_SAMPLES = 64;
constexpr int NPS       = 3 * 256 * 256;   // 196608 elements per sample
constexpr int BPS       = 32;              // blocks per sample -> 2048 blocks total (8/CU)
constexpr int CHUNK     = NPS / BPS;       // 6144 elements (divisible by 4)
constexpr int THREADS   = 256;

__device__ __forceinline__ float wave_reduce_sum(float v) {
    #pragma unroll
    for (int off = 32; off > 0; off >>= 1)
        v += __shfl_down(v, off, 64);
    return v;
}

__global__ __launch_bounds__(THREADS) void pcc_partial_kernel(
        const float* __restrict__ a, const float* __restrict__ b,
        float* __restrict__ ws) {
    const int blk = blockIdx.x;
    const int s   = blk / BPS;          // sample
    const int c   = blk % BPS;          // chunk within sample
    const size_t base = (size_t)s * NPS + (size_t)c * CHUNK;
    const float4* a4 = reinterpret_cast<const float4*>(a + base);
    const float4* b4 = reinterpret_cast<const float4*>(b + base);
    const int n4 = CHUNK / 4;           // 1536 float4 per input

    float sa = 0.f, sb = 0.f, sab = 0.f, saa = 0.f, sbb = 0.f;
    for (int i = threadIdx.x; i < n4; i += THREADS) {
        float4 va = a4[i];
        float4 vb = b4[i];
        sa  += va.x + va.y + va.z + va.w;
        sb  += vb.x + vb.y + vb.z + vb.w;
        sab = fmaf(va.x, vb.x, sab); sab = fmaf(va.y, vb.y, sab);
        sab = fmaf(va.z, vb.z, sab); sab = fmaf(va.w, vb.w, sab);
        saa = fmaf(va.x, va.x, saa); saa = fmaf(va.y, va.y, saa);
        saa = fmaf(va.z, va.z, saa); saa = fmaf(va.w, va.w, saa);
        sbb = fmaf(vb.x, vb.x, sbb); sbb = fmaf(vb.y, vb.y, sbb);
        sbb = fmaf(vb.w, vb.w, sbb); sbb = fmaf(vb.z, vb.z, sbb);
    }

    // per-wave reduce, then cross-wave combine in LDS (4 waves/block)
    sa  = wave_reduce_sum(sa);
    sb  = wave_reduce_sum(sb);
    sab = wave_reduce_sum(sab);
    saa = wave_reduce_sum(saa);
    sbb = wave_reduce_sum(sbb);

    __shared__ float lds[4][5];
    const int wid  = threadIdx.x >> 6;
    const int lane = threadIdx.x & 63;
    if (lane == 0) {
        lds[wid][0] = sa; lds[wid][1] = sb; lds[wid][2] = sab;
        lds[wid][3] = saa; lds[wid][4] = sbb;
    }
    __syncthreads();
    if (threadIdx.x == 0) {
        float r0 = 0.f, r1 = 0.f, r2 = 0.f, r3 = 0.f, r4 = 0.f;
        #pragma unroll
        for (int w = 0; w < 4; ++w) {
            r0 += lds[w][0]; r1 += lds[w][1]; r2 += lds[w][2];
            r3 += lds[w][3]; r4 += lds[w][4];
        }
        float* out = ws + (size_t)blk * 5;
        out[0] = r0; out[1] = r1; out[2] = r2; out[3] = r3; out[4] = r4;
    }
}

__global__ __launch_bounds__(64) void pcc_final_kernel(
        const float* __restrict__ ws, float* __restrict__ out) {
    const int s = threadIdx.x;   // one lane per sample, 64 lanes
    float sa = 0.f, sb = 0.f, sab = 0.f, saa = 0.f, sbb = 0.f;
    #pragma unroll
    for (int c = 0; c < BPS; ++c) {
        const float* p = ws + ((size_t)s * BPS + c) * 5;
        sa += p[0]; sb += p[1]; sab += p[2]; saa += p[3]; sbb += p[4];
    }
    const float N = (float)NPS;
    const float cov = sab - sa * sb / N;
    const float va  = saa - sa * sa / N;
    const float vb  = sbb - sb * sb / N;
    float pcc = cov / sqrtf(va * vb);
    pcc = wave_reduce_sum(pcc);
    if (s == 0) out[0] = 1.0f - pcc / (float)B_SAMPLES;
}

extern "C" void kernel_launch(void* const* d_in, const int* in_sizes, int n_in,
                              void* d_out, int out_size, void* d_ws, size_t ws_size,
                              hipStream_t stream) {
    const float* y_hat = (const float*)d_in[0];
    const float* y     = (const float*)d_in[1];
    float* out = (float*)d_out;
    float* ws  = (float*)d_ws;   // needs 64*32*5 floats = 40 KB

    pcc_partial_kernel<<<B_SAMPLES * BPS, THREADS, 0, stream>>>(y_hat, y, ws);
    pcc_final_kernel<<<1, 64, 0, stream>>>(ws, out);
}